// Round 1
// baseline (154.718 us; speedup 1.0000x reference)
//
#include <hip/hip_runtime.h>
#include <math.h>

#define EPS 1e-12f
#define EDIR 0.57735027f

#define NB 8      // batches
#define NS 256    // skel points
#define NP 4096   // shape points
#define NM 256    // l3 points

#define NSLOT 64
#define SLOTW 32

// term slots
#define T_CD1   0
#define T_CD2   1
#define T_P2SN  2
#define T_P2SJ  3
#define T_NORM  5
#define T_ND    6
#define T_NS    7
#define T_SKN_SUM 8    // +b  (8 entries)
#define T_SKN_SQ  16   // +b  (8 entries)

__device__ __forceinline__ unsigned umin2(unsigned a, unsigned b){ return a<b?a:b; }
__device__ __forceinline__ unsigned umax2(unsigned a, unsigned b){ return a>b?a:b; }

__device__ __forceinline__ float wave_min(float v){
#pragma unroll
  for (int o = 32; o; o >>= 1) v = fminf(v, __shfl_xor(v, o));
  return v;
}
__device__ __forceinline__ float wave_sum(float v){
#pragma unroll
  for (int o = 32; o; o >>= 1) v += __shfl_xor(v, o);
  return v;
}
__device__ __forceinline__ int wave_sum_i(int v){
#pragma unroll
  for (int o = 32; o; o >>= 1) v += __shfl_xor(v, o);
  return v;
}
__device__ __forceinline__ unsigned long long wave_min_u64(unsigned long long v){
#pragma unroll
  for (int o = 32; o; o >>= 1){
    unsigned long long w = __shfl_xor(v, o);
    v = (w < v) ? w : v;
  }
  return v;
}

__global__ __launch_bounds__(256) void k_zero(float* ws){
  int i = blockIdx.x * 256 + threadIdx.x;
  if (i < NSLOT * SLOTW) ws[i] = 0.0f;
}

// ---- cd1: for each (b, sample m of 2048) min over 4096 shape points ----
__global__ __launch_bounds__(256) void k_cd1(const float* __restrict__ skel,
                                             const float* __restrict__ rad,
                                             const float* __restrict__ shape,
                                             float* __restrict__ ws){
  int wid  = threadIdx.x >> 6;
  int lane = threadIdx.x & 63;
  int row  = blockIdx.x * 4 + wid;          // 0..16383
  int b = row >> 11;
  int m = row & 2047;
  int i = m >> 3, k = m & 7;
  const float* sp = skel + (b * NS + i) * 3;
  float r = rad[b * NS + i];
  float px = sp[0] + r * ((k & 4) ? -EDIR : EDIR);
  float py = sp[1] + r * ((k & 2) ? -EDIR : EDIR);
  float pz = sp[2] + r * ((k & 1) ? -EDIR : EDIR);
  const float* sh = shape + (size_t)b * NP * 6;
  float mn = 3.4e38f;
#pragma unroll 8
  for (int s = 0; s < 64; ++s){
    const float* q = sh + (s * 64 + lane) * 6;
    float dx = q[0] - px, dy = q[1] - py, dz = q[2] - pz;
    float d = fmaf(dx, dx, fmaf(dy, dy, dz * dz));
    mn = fminf(mn, d);
  }
  mn = wave_min(mn);
  if (lane == 0){
    float* slot = ws + (size_t)(row & (NSLOT - 1)) * SLOTW;
    atomicAdd(slot + T_CD1, sqrtf(fmaxf(mn, EPS)));
  }
}

// ---- cd2 + p2s_n: for each (b, shape point n) ----
__global__ __launch_bounds__(256) void k_cd2_p2sn(const float* __restrict__ skel,
                                                  const float* __restrict__ rad,
                                                  const float* __restrict__ shape,
                                                  float* __restrict__ ws){
  int wid  = threadIdx.x >> 6;
  int lane = threadIdx.x & 63;
  int row  = blockIdx.x * 4 + wid;          // 0..32767
  int b = row >> 12;
  int n = row & 4095;
  const float* q = shape + ((size_t)b * NP + n) * 6;
  float px = q[0], py = q[1], pz = q[2];
  const float* sk = skel + (size_t)b * NS * 3;
  const float* rd = rad + (size_t)b * NS;

  // cd2: min over 2048 samples
  float mn = 3.4e38f;
#pragma unroll 4
  for (int it = 0; it < 32; ++it){
    int mm = it * 64 + lane;
    int i = mm >> 3, k = mm & 7;
    float r = rd[i];
    float sx = sk[i * 3 + 0] + r * ((k & 4) ? -EDIR : EDIR);
    float sy = sk[i * 3 + 1] + r * ((k & 2) ? -EDIR : EDIR);
    float sz = sk[i * 3 + 2] + r * ((k & 1) ? -EDIR : EDIR);
    float dx = px - sx, dy = py - sy, dz = pz - sz;
    mn = fminf(mn, fmaf(dx, dx, fmaf(dy, dy, dz * dz)));
  }
  mn = wave_min(mn);

  // p2s_n: min over 256 skel of |dist - r|
  float pm = 3.4e38f;
#pragma unroll
  for (int it = 0; it < 4; ++it){
    int j = it * 64 + lane;
    float dx = px - sk[j * 3 + 0], dy = py - sk[j * 3 + 1], dz = pz - sk[j * 3 + 2];
    float d = sqrtf(fmaxf(fmaf(dx, dx, fmaf(dy, dy, dz * dz)), EPS));
    pm = fminf(pm, fabsf(d - rd[j]));
  }
  pm = wave_min(pm);

  if (lane == 0){
    float* slot = ws + (size_t)(row & (NSLOT - 1)) * SLOTW;
    atomicAdd(slot + T_CD2, sqrtf(fmaxf(mn, EPS)));
    atomicAdd(slot + T_P2SN, pm);
  }
}

// ---- per (b, skel j): p2s_j + top30 normal term + top3 ns term + nd term ----
__global__ __launch_bounds__(256) void k_skelrow(const float* __restrict__ skel,
                                                 const float* __restrict__ rad,
                                                 const float* __restrict__ nori,
                                                 const float* __restrict__ shape,
                                                 float* __restrict__ ws){
  int wid  = threadIdx.x >> 6;
  int lane = threadIdx.x & 63;
  int row  = blockIdx.x * 4 + wid;          // 0..2047
  int b = row >> 8;
  int j = row & 255;
  const float* sj = skel + (size_t)(b * NS + j) * 3;
  float cx = sj[0], cy = sj[1], cz = sj[2];
  float rj = rad[b * NS + j];
  const float* njp = nori + (size_t)(b * NS + j) * 3;
  float nx = njp[0], ny = njp[1], nz = njp[2];
  const float* sh = shape + (size_t)b * NP * 6;

  unsigned m0=~0u,m1=~0u,m2=~0u,m3=~0u,m4=~0u,m5=~0u,m6=~0u,m7=~0u;
  unsigned dbits[64];
  float pmin = 3.4e38f;

#pragma unroll
  for (int s = 0; s < 64; ++s){
    const float* q = sh + (s * 64 + lane) * 6;
    float dx = q[0] - cx, dy = q[1] - cy, dz = q[2] - cz;
    float dsq = fmaf(dx, dx, fmaf(dy, dy, dz * dz));
    float d = sqrtf(fmaxf(dsq, EPS));
    pmin = fminf(pmin, fabsf(d - rj));
    unsigned u = __float_as_uint(dsq);
    dbits[s] = u;
    // branchless insert into sorted top-8 (ascending)
    m7 = umin2(m7, u);
    { unsigned a = umin2(m6, m7), bb = umax2(m6, m7); m6 = a; m7 = bb; }
    { unsigned a = umin2(m5, m6), bb = umax2(m5, m6); m5 = a; m6 = bb; }
    { unsigned a = umin2(m4, m5), bb = umax2(m4, m5); m4 = a; m5 = bb; }
    { unsigned a = umin2(m3, m4), bb = umax2(m3, m4); m3 = a; m4 = bb; }
    { unsigned a = umin2(m2, m3), bb = umax2(m2, m3); m2 = a; m3 = bb; }
    { unsigned a = umin2(m1, m2), bb = umax2(m1, m2); m1 = a; m2 = bb; }
    { unsigned a = umin2(m0, m1), bb = umax2(m0, m1); m0 = a; m1 = bb; }
  }
  pmin = wave_min(pmin);

  // binary search for the 30th smallest squared-distance (as uint bits)
  unsigned lo = 0u, hi = 0x7F800000u;
  while (lo < hi){
    unsigned mid = lo + ((hi - lo) >> 1);
    int c = (m0<=mid)+(m1<=mid)+(m2<=mid)+(m3<=mid)+(m4<=mid)+(m5<=mid)+(m6<=mid)+(m7<=mid);
    c = wave_sum_i(c);
    if (c >= 30) hi = mid; else lo = mid + 1;
  }
  unsigned tau = hi;

  // accumulate |dot(nori_j, normal_n)| over the 30 nearest
  float dsum = 0.0f;
#pragma unroll
  for (int s = 0; s < 64; ++s){
    if (dbits[s] <= tau){
      const float* q = sh + (s * 64 + lane) * 6;
      float dt = fmaf(nx, q[3], fmaf(ny, q[4], nz * q[5]));
      dsum += fabsf(dt);
    }
  }
  dsum = wave_sum(dsum);

  // ns: 3 nearest skel points (incl. self), sum ||nori_j - nori_k||
  const float* skb = skel + (size_t)b * NS * 3;
  const float* nb  = nori + (size_t)b * NS * 3;
  unsigned u0=~0u,u1=~0u,u2=~0u; int i0=0,i1=0,i2=0;
#pragma unroll
  for (int it = 0; it < 4; ++it){
    int n2 = it * 64 + lane;
    float dx = skb[n2*3+0]-cx, dy = skb[n2*3+1]-cy, dz = skb[n2*3+2]-cz;
    unsigned u = __float_as_uint(fmaf(dx,dx,fmaf(dy,dy,dz*dz)));
    if (u < u2){ u2 = u; i2 = n2; }
    if (u2 < u1){ unsigned t=u1;u1=u2;u2=t; int ti=i1;i1=i2;i2=ti; }
    if (u1 < u0){ unsigned t=u0;u0=u1;u1=t; int ti=i0;i0=i1;i1=ti; }
  }
  int cc = 0;
  float nssum = 0.0f;
#pragma unroll
  for (int r = 0; r < 3; ++r){
    unsigned hu = (cc==0)?u0:((cc==1)?u1:u2);
    int      hix= (cc==0)?i0:((cc==1)?i1:i2);
    unsigned long long pack = (((unsigned long long)hu) << 32) | (unsigned)hix;
    unsigned long long best = wave_min_u64(pack);
    if (pack == best) cc++;
    int idx = (int)(best & 0xffffffffull);
    if (lane == 0){
      float ax = nb[idx*3+0]-nx, ay = nb[idx*3+1]-ny, az = nb[idx*3+2]-nz;
      nssum += sqrtf(fmaf(ax,ax,fmaf(ay,ay,az*az)) + EPS);
    }
  }

  if (lane == 0){
    float nrm = sqrtf(nx*nx + ny*ny + nz*nz + EPS);
    float ndv = expf(0.3f - nrm) + ((nrm < 0.25f) ? 5.0f : 0.0f);
    float* slot = ws + (size_t)(row & (NSLOT - 1)) * SLOTW;
    atomicAdd(slot + T_P2SJ, pmin);
    atomicAdd(slot + T_NORM, dsum * (1.0f / 30.0f));
    atomicAdd(slot + T_NS,   nssum);
    atomicAdd(slot + T_ND,   ndv);
  }
}

// ---- skn: thread per combine point (B*7680), min over 256 l3 points ----
__global__ __launch_bounds__(256) void k_skn(const float* __restrict__ skel,
                                             const float* __restrict__ nori,
                                             const float* __restrict__ l3,
                                             float* __restrict__ ws){
  int b = blockIdx.x / 30;
  int t = (blockIdx.x % 30) * 256 + threadIdx.x;   // 0..7679
  int s = t >> 8;
  int j = t & 255;
  float ksf = (float)s * (1.0f / 30.0f);
  const float* sj = skel + (size_t)(b * NS + j) * 3;
  const float* nj = nori + (size_t)(b * NS + j) * 3;
  float px = fmaf(nj[0], ksf, sj[0]);
  float py = fmaf(nj[1], ksf, sj[1]);
  float pz = fmaf(nj[2], ksf, sj[2]);
  const float* lb = l3 + (size_t)b * NM * 3;
  float mn = 3.4e38f;
#pragma unroll 4
  for (int q = 0; q < NM; ++q){
    float dx = lb[q*3+0]-px, dy = lb[q*3+1]-py, dz = lb[q*3+2]-pz;
    mn = fminf(mn, fmaf(dx,dx,fmaf(dy,dy,dz*dz)));
  }
  float d = sqrtf(fmaxf(mn, EPS));
  float s1 = wave_sum(d);
  float s2 = wave_sum(d * d);
  __shared__ float r1[4], r2[4];
  int wid = threadIdx.x >> 6, lane = threadIdx.x & 63;
  if (lane == 0){ r1[wid] = s1; r2[wid] = s2; }
  __syncthreads();
  if (threadIdx.x == 0){
    float a1 = r1[0]+r1[1]+r1[2]+r1[3];
    float a2 = r2[0]+r2[1]+r2[2]+r2[3];
    float* slot = ws + (size_t)(blockIdx.x & (NSLOT - 1)) * SLOTW;
    atomicAdd(slot + T_SKN_SUM + b, a1);
    atomicAdd(slot + T_SKN_SQ  + b, a2);
  }
}

// ---- finalize ----
__global__ __launch_bounds__(256) void k_final(const float* __restrict__ rad,
                                               const float* __restrict__ ws,
                                               const int* w0, const int* w1, const int* w2,
                                               const int* w4, const int* w5, const int* w6,
                                               float* __restrict__ out){
  __shared__ float A[SLOTW];
  __shared__ float rs[256];
  int tid = threadIdx.x;
  if (tid < SLOTW){
    float v = 0.0f;
    for (int s = 0; s < NSLOT; ++s) v += ws[(size_t)s * SLOTW + tid];
    A[tid] = v;
  }
  float r = 0.0f;
  for (int q = tid; q < NB * NS; q += 256) r += rad[q];
  rs[tid] = r;
  __syncthreads();
  if (tid == 0){
    float srad = 0.0f;
    for (int q = 0; q < 256; ++q) srad += rs[q];
    float ls = A[T_CD1] * (1.0f/2048.0f) + A[T_CD2] * (1.0f/4096.0f);
    float lp = A[T_P2SN] * (1.0f/4096.0f) + A[T_P2SJ] * (1.0f/256.0f);
    float lr = -srad * (1.0f/256.0f);
    float ln = A[T_NORM] * (1.0f/8.0f);
    float smind = 0.0f, vsum = 0.0f;
    for (int bb = 0; bb < NB; ++bb){
      float s1 = A[T_SKN_SUM + bb], s2 = A[T_SKN_SQ + bb];
      smind += s1;
      vsum  += (s2 - s1 * s1 * (1.0f/7680.0f)) * (1.0f/7679.0f);
    }
    float lskn = 50.0f * smind * (1.0f/(8.0f*7680.0f)) + 500.0f * vsum * (1.0f/8.0f);
    float lnd = A[T_ND] * (1.0f/2048.0f);
    float lns = A[T_NS] * (1.0f/6144.0f);
    float o = (float)w0[0]*ls + (float)w1[0]*lp + (float)w2[0]*lr +
              (float)w4[0]*ln + (float)w5[0]*lskn + (float)w6[0]*lnd + 0.1f*lns;
    out[0] = o;
  }
}

extern "C" void kernel_launch(void* const* d_in, const int* in_sizes, int n_in,
                              void* d_out, int out_size, void* d_ws, size_t ws_size,
                              hipStream_t stream) {
  const float* skel  = (const float*)d_in[0];
  const float* rad   = (const float*)d_in[1];
  const float* nori  = (const float*)d_in[3];
  const float* l3    = (const float*)d_in[5];
  const float* shape = (const float*)d_in[7];
  const int* w0 = (const int*)d_in[9];
  const int* w1 = (const int*)d_in[10];
  const int* w2 = (const int*)d_in[11];
  const int* w4 = (const int*)d_in[13];
  const int* w5 = (const int*)d_in[14];
  const int* w6 = (const int*)d_in[15];
  float* ws  = (float*)d_ws;
  float* out = (float*)d_out;

  k_zero<<<dim3((NSLOT * SLOTW + 255) / 256), dim3(256), 0, stream>>>(ws);
  k_cd1<<<dim3(4096), dim3(256), 0, stream>>>(skel, rad, shape, ws);
  k_cd2_p2sn<<<dim3(8192), dim3(256), 0, stream>>>(skel, rad, shape, ws);
  k_skelrow<<<dim3(512), dim3(256), 0, stream>>>(skel, rad, nori, shape, ws);
  k_skn<<<dim3(240), dim3(256), 0, stream>>>(skel, nori, l3, ws);
  k_final<<<dim3(1), dim3(256), 0, stream>>>(rad, ws, w0, w1, w2, w4, w5, w6, out);
}

// Round 2
// 88.785 us; speedup vs baseline: 1.7426x; 1.7426x over previous
//
#include <hip/hip_runtime.h>
#include <math.h>

#define EPS 1e-12f
#define EDIR 0.57735027f

#define NB 8      // batches
#define NS 256    // skel points
#define NP 4096   // shape points
#define NM 256    // l3 points

#define NSLOT 64
#define SLOTW 32
#define ACC_F (NSLOT * SLOTW)

// term slots
#define T_CD1   0
#define T_CD2   1
#define T_P2SN  2
#define T_P2SJ  3
#define T_NORM  5
#define T_ND    6
#define T_NS    7
#define T_SKN_SUM 8    // +b  (8 entries)
#define T_SKN_SQ  16   // +b  (8 entries)

__device__ __forceinline__ unsigned umin2(unsigned a, unsigned b){ return a<b?a:b; }
__device__ __forceinline__ unsigned umax2(unsigned a, unsigned b){ return a>b?a:b; }

__device__ __forceinline__ float wave_min(float v){
#pragma unroll
  for (int o = 32; o; o >>= 1) v = fminf(v, __shfl_xor(v, o));
  return v;
}
__device__ __forceinline__ float wave_sum(float v){
#pragma unroll
  for (int o = 32; o; o >>= 1) v += __shfl_xor(v, o);
  return v;
}
__device__ __forceinline__ int wave_sum_i(int v){
#pragma unroll
  for (int o = 32; o; o >>= 1) v += __shfl_xor(v, o);
  return v;
}
__device__ __forceinline__ unsigned long long wave_min_u64(unsigned long long v){
#pragma unroll
  for (int o = 32; o; o >>= 1){
    unsigned long long w = __shfl_xor(v, o);
    v = (w < v) ? w : v;
  }
  return v;
}

// ws layout (floats):
//   acc   : ACC_F                      @ 0
//   smp   : NB*2048 float4             @ ACC_F
//   skr   : NB*NS   float4  (x,y,z,r)
//   sxy   : NB*NP   float4  (x,y,z,0)
//   l3p   : NB*NM   float4
//   nr4   : NB*NS   float4
#define OFF_SMP (ACC_F)
#define OFF_SKR (OFF_SMP + NB*2048*4)
#define OFF_SXY (OFF_SKR + NB*NS*4)
#define OFF_L3P (OFF_SXY + NB*NP*4)
#define OFF_NR4 (OFF_L3P + NB*NM*4)

__global__ __launch_bounds__(256) void k_prep(const float* __restrict__ skel,
                                              const float* __restrict__ rad,
                                              const float* __restrict__ nori,
                                              const float* __restrict__ l3,
                                              const float* __restrict__ shape,
                                              float* __restrict__ ws){
  int i = blockIdx.x * 256 + threadIdx.x;   // 0..32767
  float4* smp = (float4*)(ws + OFF_SMP);
  float4* skr = (float4*)(ws + OFF_SKR);
  float4* sxy = (float4*)(ws + OFF_SXY);
  float4* l3p = (float4*)(ws + OFF_L3P);
  float4* nr4 = (float4*)(ws + OFF_NR4);
  if (i < ACC_F) ws[i] = 0.0f;
  {
    const float* q = shape + (size_t)i * 6;
    sxy[i] = make_float4(q[0], q[1], q[2], 0.0f);
  }
  if (i < NB * 2048){
    int b = i >> 11, m = i & 2047;
    int si = m >> 3, k = m & 7;
    const float* sp = skel + (size_t)(b * NS + si) * 3;
    float r = rad[b * NS + si];
    smp[i] = make_float4(sp[0] + r * ((k & 4) ? -EDIR : EDIR),
                         sp[1] + r * ((k & 2) ? -EDIR : EDIR),
                         sp[2] + r * ((k & 1) ? -EDIR : EDIR), 0.0f);
  }
  if (i < NB * NS){
    const float* sp = skel + (size_t)i * 3;
    skr[i] = make_float4(sp[0], sp[1], sp[2], rad[i]);
    const float* nn = nori + (size_t)i * 3;
    nr4[i] = make_float4(nn[0], nn[1], nn[2], 0.0f);
    const float* lp = l3 + (size_t)i * 3;
    l3p[i] = make_float4(lp[0], lp[1], lp[2], 0.0f);
  }
}

// ---- cd1: 4 sample-rows per wave, lanes sweep 4096 shape points ----
__global__ __launch_bounds__(256) void k_cd1(float* __restrict__ ws){
  const float4* smp = (const float4*)(ws + OFF_SMP);
  const float4* sxy = (const float4*)(ws + OFF_SXY);
  int wid  = threadIdx.x >> 6;
  int lane = threadIdx.x & 63;
  int wg   = blockIdx.x * 4 + wid;       // 0..4095
  int row0 = wg * 4;                     // (b,m) flat, groups of 4 stay in-batch
  int b    = row0 >> 11;
  float4 c0 = smp[row0], c1 = smp[row0+1], c2 = smp[row0+2], c3 = smp[row0+3];
  const float4* sh = sxy + (size_t)b * NP;
  float n0 = 3.4e38f, n1 = 3.4e38f, n2 = 3.4e38f, n3 = 3.4e38f;
#pragma unroll 8
  for (int s = 0; s < 64; ++s){
    float4 p = sh[s * 64 + lane];
    float dx, dy, dz, d;
    dx = p.x - c0.x; dy = p.y - c0.y; dz = p.z - c0.z;
    d = fmaf(dx, dx, fmaf(dy, dy, dz * dz)); n0 = fminf(n0, d);
    dx = p.x - c1.x; dy = p.y - c1.y; dz = p.z - c1.z;
    d = fmaf(dx, dx, fmaf(dy, dy, dz * dz)); n1 = fminf(n1, d);
    dx = p.x - c2.x; dy = p.y - c2.y; dz = p.z - c2.z;
    d = fmaf(dx, dx, fmaf(dy, dy, dz * dz)); n2 = fminf(n2, d);
    dx = p.x - c3.x; dy = p.y - c3.y; dz = p.z - c3.z;
    d = fmaf(dx, dx, fmaf(dy, dy, dz * dz)); n3 = fminf(n3, d);
  }
  n0 = wave_min(n0); n1 = wave_min(n1); n2 = wave_min(n2); n3 = wave_min(n3);
  if (lane == 0){
    float v = sqrtf(fmaxf(n0, EPS)) + sqrtf(fmaxf(n1, EPS)) +
              sqrtf(fmaxf(n2, EPS)) + sqrtf(fmaxf(n3, EPS));
    atomicAdd(ws + (size_t)(wg & (NSLOT - 1)) * SLOTW + T_CD1, v);
  }
}

// ---- cd2 + p2s_n: 4 shape-rows per wave ----
__global__ __launch_bounds__(256) void k_cd2_p2sn(float* __restrict__ ws){
  const float4* smp = (const float4*)(ws + OFF_SMP);
  const float4* skr = (const float4*)(ws + OFF_SKR);
  const float4* sxy = (const float4*)(ws + OFF_SXY);
  int wid  = threadIdx.x >> 6;
  int lane = threadIdx.x & 63;
  int wg   = blockIdx.x * 4 + wid;       // 0..8191
  int row0 = wg * 4;                     // (b,n) flat
  int b    = row0 >> 12;
  float4 c0 = sxy[row0], c1 = sxy[row0+1], c2 = sxy[row0+2], c3 = sxy[row0+3];
  const float4* sb = smp + (size_t)b * 2048;
  float n0 = 3.4e38f, n1 = 3.4e38f, n2 = 3.4e38f, n3 = 3.4e38f;
#pragma unroll 8
  for (int it = 0; it < 32; ++it){
    float4 s = sb[it * 64 + lane];
    float dx, dy, dz, d;
    dx = c0.x - s.x; dy = c0.y - s.y; dz = c0.z - s.z;
    d = fmaf(dx, dx, fmaf(dy, dy, dz * dz)); n0 = fminf(n0, d);
    dx = c1.x - s.x; dy = c1.y - s.y; dz = c1.z - s.z;
    d = fmaf(dx, dx, fmaf(dy, dy, dz * dz)); n1 = fminf(n1, d);
    dx = c2.x - s.x; dy = c2.y - s.y; dz = c2.z - s.z;
    d = fmaf(dx, dx, fmaf(dy, dy, dz * dz)); n2 = fminf(n2, d);
    dx = c3.x - s.x; dy = c3.y - s.y; dz = c3.z - s.z;
    d = fmaf(dx, dx, fmaf(dy, dy, dz * dz)); n3 = fminf(n3, d);
  }
  n0 = wave_min(n0); n1 = wave_min(n1); n2 = wave_min(n2); n3 = wave_min(n3);

  const float4* kb = skr + (size_t)b * NS;
  float p0 = 3.4e38f, p1 = 3.4e38f, p2 = 3.4e38f, p3 = 3.4e38f;
#pragma unroll
  for (int it = 0; it < 4; ++it){
    float4 kr = kb[it * 64 + lane];
    float dx, dy, dz, d;
    dx = c0.x - kr.x; dy = c0.y - kr.y; dz = c0.z - kr.z;
    d = sqrtf(fmaxf(fmaf(dx, dx, fmaf(dy, dy, dz * dz)), EPS));
    p0 = fminf(p0, fabsf(d - kr.w));
    dx = c1.x - kr.x; dy = c1.y - kr.y; dz = c1.z - kr.z;
    d = sqrtf(fmaxf(fmaf(dx, dx, fmaf(dy, dy, dz * dz)), EPS));
    p1 = fminf(p1, fabsf(d - kr.w));
    dx = c2.x - kr.x; dy = c2.y - kr.y; dz = c2.z - kr.z;
    d = sqrtf(fmaxf(fmaf(dx, dx, fmaf(dy, dy, dz * dz)), EPS));
    p2 = fminf(p2, fabsf(d - kr.w));
    dx = c3.x - kr.x; dy = c3.y - kr.y; dz = c3.z - kr.z;
    d = sqrtf(fmaxf(fmaf(dx, dx, fmaf(dy, dy, dz * dz)), EPS));
    p3 = fminf(p3, fabsf(d - kr.w));
  }
  p0 = wave_min(p0); p1 = wave_min(p1); p2 = wave_min(p2); p3 = wave_min(p3);

  if (lane == 0){
    float* slot = ws + (size_t)(wg & (NSLOT - 1)) * SLOTW;
    atomicAdd(slot + T_CD2, sqrtf(fmaxf(n0, EPS)) + sqrtf(fmaxf(n1, EPS)) +
                            sqrtf(fmaxf(n2, EPS)) + sqrtf(fmaxf(n3, EPS)));
    atomicAdd(slot + T_P2SN, p0 + p1 + p2 + p3);
  }
}

// ---- per (b, skel j): p2s_j + top30 normal term + top3 ns term + nd term ----
__global__ __launch_bounds__(256) void k_skelrow(const float* __restrict__ shape,
                                                 float* __restrict__ ws){
  const float4* skr = (const float4*)(ws + OFF_SKR);
  const float4* sxy = (const float4*)(ws + OFF_SXY);
  const float4* nr4 = (const float4*)(ws + OFF_NR4);
  int wid  = threadIdx.x >> 6;
  int lane = threadIdx.x & 63;
  int row  = blockIdx.x * 4 + wid;          // 0..2047
  int b = row >> 8;
  float4 sj = skr[row];
  float cx = sj.x, cy = sj.y, cz = sj.z, rj = sj.w;
  float4 nj = nr4[row];
  float nx = nj.x, ny = nj.y, nz = nj.z;
  const float4* sh = sxy + (size_t)b * NP;

  unsigned m0=~0u,m1=~0u,m2=~0u,m3=~0u,m4=~0u,m5=~0u,m6=~0u,m7=~0u;
  unsigned dbits[64];
  float pmin = 3.4e38f;

#pragma unroll
  for (int s = 0; s < 64; ++s){
    float4 q = sh[s * 64 + lane];
    float dx = q.x - cx, dy = q.y - cy, dz = q.z - cz;
    float dsq = fmaf(dx, dx, fmaf(dy, dy, dz * dz));
    float d = sqrtf(fmaxf(dsq, EPS));
    pmin = fminf(pmin, fabsf(d - rj));
    unsigned u = __float_as_uint(dsq);
    dbits[s] = u;
    m7 = umin2(m7, u);
    { unsigned a = umin2(m6, m7), bb = umax2(m6, m7); m6 = a; m7 = bb; }
    { unsigned a = umin2(m5, m6), bb = umax2(m5, m6); m5 = a; m6 = bb; }
    { unsigned a = umin2(m4, m5), bb = umax2(m4, m5); m4 = a; m5 = bb; }
    { unsigned a = umin2(m3, m4), bb = umax2(m3, m4); m3 = a; m4 = bb; }
    { unsigned a = umin2(m2, m3), bb = umax2(m2, m3); m2 = a; m3 = bb; }
    { unsigned a = umin2(m1, m2), bb = umax2(m1, m2); m1 = a; m2 = bb; }
    { unsigned a = umin2(m0, m1), bb = umax2(m0, m1); m0 = a; m1 = bb; }
  }
  pmin = wave_min(pmin);

  unsigned lo = 0u, hi = 0x7F800000u;
  while (lo < hi){
    unsigned mid = lo + ((hi - lo) >> 1);
    int c = (m0<=mid)+(m1<=mid)+(m2<=mid)+(m3<=mid)+(m4<=mid)+(m5<=mid)+(m6<=mid)+(m7<=mid);
    c = wave_sum_i(c);
    if (c >= 30) hi = mid; else lo = mid + 1;
  }
  unsigned tau = hi;

  float dsum = 0.0f;
  const float* shn = shape + (size_t)b * NP * 6;
#pragma unroll
  for (int s = 0; s < 64; ++s){
    if (dbits[s] <= tau){
      const float* q = shn + (s * 64 + lane) * 6;
      float dt = fmaf(nx, q[3], fmaf(ny, q[4], nz * q[5]));
      dsum += fabsf(dt);
    }
  }
  dsum = wave_sum(dsum);

  const float4* skb = skr + (size_t)b * NS;
  const float4* nb  = nr4 + (size_t)b * NS;
  unsigned u0=~0u,u1=~0u,u2=~0u; int i0=0,i1=0,i2=0;
#pragma unroll
  for (int it = 0; it < 4; ++it){
    int n2i = it * 64 + lane;
    float4 kk = skb[n2i];
    float dx = kk.x - cx, dy = kk.y - cy, dz = kk.z - cz;
    unsigned u = __float_as_uint(fmaf(dx,dx,fmaf(dy,dy,dz*dz)));
    if (u < u2){ u2 = u; i2 = n2i; }
    if (u2 < u1){ unsigned t=u1;u1=u2;u2=t; int ti=i1;i1=i2;i2=ti; }
    if (u1 < u0){ unsigned t=u0;u0=u1;u1=t; int ti=i0;i0=i1;i1=ti; }
  }
  int cc = 0;
  float nssum = 0.0f;
#pragma unroll
  for (int r = 0; r < 3; ++r){
    unsigned hu = (cc==0)?u0:((cc==1)?u1:u2);
    int      hix= (cc==0)?i0:((cc==1)?i1:i2);
    unsigned long long pack = (((unsigned long long)hu) << 32) | (unsigned)hix;
    unsigned long long best = wave_min_u64(pack);
    if (pack == best) cc++;
    int idx = (int)(best & 0xffffffffull);
    if (lane == 0){
      float4 nn = nb[idx];
      float ax = nn.x-nx, ay = nn.y-ny, az = nn.z-nz;
      nssum += sqrtf(fmaf(ax,ax,fmaf(ay,ay,az*az)) + EPS);
    }
  }

  if (lane == 0){
    float nrm = sqrtf(nx*nx + ny*ny + nz*nz + EPS);
    float ndv = expf(0.3f - nrm) + ((nrm < 0.25f) ? 5.0f : 0.0f);
    float* slot = ws + (size_t)(row & (NSLOT - 1)) * SLOTW;
    atomicAdd(slot + T_P2SJ, pmin);
    atomicAdd(slot + T_NORM, dsum * (1.0f / 30.0f));
    atomicAdd(slot + T_NS,   nssum);
    atomicAdd(slot + T_ND,   ndv);
  }
}

// ---- skn: thread per combine point (B*7680), min over 256 l3 points ----
__global__ __launch_bounds__(256) void k_skn(float* __restrict__ ws){
  const float4* skr = (const float4*)(ws + OFF_SKR);
  const float4* nr4 = (const float4*)(ws + OFF_NR4);
  const float4* l3p = (const float4*)(ws + OFF_L3P);
  __shared__ float4 lsh[NM];
  int b = blockIdx.x / 30;
  int t = (blockIdx.x % 30) * 256 + threadIdx.x;   // 0..7679
  lsh[threadIdx.x] = l3p[(size_t)b * NM + threadIdx.x];
  __syncthreads();
  int s = t >> 8;
  int j = t & 255;
  float ksf = (float)s * (1.0f / 30.0f);
  float4 sj = skr[(size_t)b * NS + j];
  float4 nj = nr4[(size_t)b * NS + j];
  float px = fmaf(nj.x, ksf, sj.x);
  float py = fmaf(nj.y, ksf, sj.y);
  float pz = fmaf(nj.z, ksf, sj.z);
  float mn = 3.4e38f;
#pragma unroll 8
  for (int q = 0; q < NM; ++q){
    float4 L = lsh[q];
    float dx = L.x - px, dy = L.y - py, dz = L.z - pz;
    mn = fminf(mn, fmaf(dx, dx, fmaf(dy, dy, dz * dz)));
  }
  float d = sqrtf(fmaxf(mn, EPS));
  float s1 = wave_sum(d);
  float s2 = wave_sum(d * d);
  __shared__ float r1[4], r2[4];
  int wid = threadIdx.x >> 6, lane = threadIdx.x & 63;
  if (lane == 0){ r1[wid] = s1; r2[wid] = s2; }
  __syncthreads();
  if (threadIdx.x == 0){
    float a1 = r1[0]+r1[1]+r1[2]+r1[3];
    float a2 = r2[0]+r2[1]+r2[2]+r2[3];
    float* slot = ws + (size_t)(blockIdx.x & (NSLOT - 1)) * SLOTW;
    atomicAdd(slot + T_SKN_SUM + b, a1);
    atomicAdd(slot + T_SKN_SQ  + b, a2);
  }
}

// ---- finalize ----
__global__ __launch_bounds__(256) void k_final(const float* __restrict__ rad,
                                               const float* __restrict__ ws,
                                               const int* w0, const int* w1, const int* w2,
                                               const int* w4, const int* w5, const int* w6,
                                               float* __restrict__ out){
  __shared__ float A[SLOTW];
  __shared__ float rs[256];
  int tid = threadIdx.x;
  if (tid < SLOTW){
    float v = 0.0f;
    for (int s = 0; s < NSLOT; ++s) v += ws[(size_t)s * SLOTW + tid];
    A[tid] = v;
  }
  float r = 0.0f;
  for (int q = tid; q < NB * NS; q += 256) r += rad[q];
  rs[tid] = r;
  __syncthreads();
  if (tid == 0){
    float srad = 0.0f;
    for (int q = 0; q < 256; ++q) srad += rs[q];
    float ls = A[T_CD1] * (1.0f/2048.0f) + A[T_CD2] * (1.0f/4096.0f);
    float lp = A[T_P2SN] * (1.0f/4096.0f) + A[T_P2SJ] * (1.0f/256.0f);
    float lr = -srad * (1.0f/256.0f);
    float ln = A[T_NORM] * (1.0f/8.0f);
    float smind = 0.0f, vsum = 0.0f;
    for (int bb = 0; bb < NB; ++bb){
      float s1 = A[T_SKN_SUM + bb], s2 = A[T_SKN_SQ + bb];
      smind += s1;
      vsum  += (s2 - s1 * s1 * (1.0f/7680.0f)) * (1.0f/7679.0f);
    }
    float lskn = 50.0f * smind * (1.0f/(8.0f*7680.0f)) + 500.0f * vsum * (1.0f/8.0f);
    float lnd = A[T_ND] * (1.0f/2048.0f);
    float lns = A[T_NS] * (1.0f/6144.0f);
    float o = (float)w0[0]*ls + (float)w1[0]*lp + (float)w2[0]*lr +
              (float)w4[0]*ln + (float)w5[0]*lskn + (float)w6[0]*lnd + 0.1f*lns;
    out[0] = o;
  }
}

extern "C" void kernel_launch(void* const* d_in, const int* in_sizes, int n_in,
                              void* d_out, int out_size, void* d_ws, size_t ws_size,
                              hipStream_t stream) {
  const float* skel  = (const float*)d_in[0];
  const float* rad   = (const float*)d_in[1];
  const float* nori  = (const float*)d_in[3];
  const float* l3    = (const float*)d_in[5];
  const float* shape = (const float*)d_in[7];
  const int* w0 = (const int*)d_in[9];
  const int* w1 = (const int*)d_in[10];
  const int* w2 = (const int*)d_in[11];
  const int* w4 = (const int*)d_in[13];
  const int* w5 = (const int*)d_in[14];
  const int* w6 = (const int*)d_in[15];
  float* ws  = (float*)d_ws;
  float* out = (float*)d_out;

  k_prep<<<dim3(128), dim3(256), 0, stream>>>(skel, rad, nori, l3, shape, ws);
  k_cd1<<<dim3(1024), dim3(256), 0, stream>>>(ws);
  k_cd2_p2sn<<<dim3(2048), dim3(256), 0, stream>>>(ws);
  k_skelrow<<<dim3(512), dim3(256), 0, stream>>>(shape, ws);
  k_skn<<<dim3(240), dim3(256), 0, stream>>>(ws);
  k_final<<<dim3(1), dim3(256), 0, stream>>>(rad, ws, w0, w1, w2, w4, w5, w6, out);
}